// Round 5
// baseline (148.702 us; speedup 1.0000x reference)
//
#include <hip/hip_runtime.h>
#include <stdint.h>

typedef unsigned char      u8;
typedef unsigned int       u32;

#define N_ROWS 8192
#define N_HALF 4096
#define DDIM   1024
#define TILE   128
#define BKB    128             // K-bytes staged per iter (=128 fp8 elems)
#define NKT    (DDIM / BKB)    // 8
#define NBLK_PREP 1024
#define NPAIRS 1056            // sum over by of ceil((by+1)/2), 64 tile-rows

typedef int   i32x4 __attribute__((ext_vector_type(4)));
typedef int   i32x8 __attribute__((ext_vector_type(8)));
typedef float f32x4 __attribute__((ext_vector_type(4)));

// ---- workspace (~8.04 MB): every byte written before read; zero atomics ----
#define OFF_X8   ((size_t)0)
#define SZ_X8    ((size_t)N_ROWS * DDIM)          // 8 MB fp8 [source;target]
#define OFF_SQ   (SZ_X8)                          // 8192 f32 row sq-norms (fp8-consistent)
#define OFF_SQP  (OFF_SQ + (size_t)N_ROWS * 4)    // sqpart[1024]
#define OFF_TS   (OFF_SQP + (size_t)NBLK_PREP * 4)// tilesum[1056]
#define WS_NEED  (OFF_TS + (size_t)NPAIRS * 4)

#define AS1(p) ((__attribute__((address_space(1))) void*)(p))
#define AS3(p) ((__attribute__((address_space(3))) void*)(p))

// ---------------------------------------------------------------------------
// Kernel A: fp32 -> fp8(e4m3, RNE HW cvt) copy, row sq-norms from DEQUANTIZED
// fp8 values (keeps diagonal L2 ~ 0), per-block sum-of-sq partial.
// 1024 blocks x 256 threads, 2 rows/wave. (R0-validated, untouched)
// ---------------------------------------------------------------------------
__global__ __launch_bounds__(256) void prep_kernel(const float* __restrict__ src,
                                                   const float* __restrict__ tgt,
                                                   u32* __restrict__ xb,
                                                   float* __restrict__ sqv,
                                                   float* __restrict__ sqpart) {
  __shared__ float wsq[4];
  const int tid  = threadIdx.x;
  const int lane = tid & 63;
  const int wave = tid >> 6;
  const int gw   = blockIdx.x * 4 + wave;     // 0..4095
  float wsum = 0.f;                           // valid on lane 0
#pragma unroll
  for (int rr = 0; rr < 2; ++rr) {
    const int r = gw * 2 + rr;                // 0..8191
    const float* rowp = (r < N_HALF) ? (src + (size_t)r * DDIM)
                                     : (tgt + (size_t)(r - N_HALF) * DDIM);
    float s = 0.f;
#pragma unroll
    for (int chn = 0; chn < 4; ++chn) {
      const int c0 = chn * 256 + lane * 4;
      float4 v = *(const float4*)(rowp + c0);
      int p = __builtin_amdgcn_cvt_pk_fp8_f32(v.x, v.y, 0, false);
      p     = __builtin_amdgcn_cvt_pk_fp8_f32(v.z, v.w, p, true);
      xb[(size_t)r * 256 + (c0 >> 2)] = (u32)p;
      float fx = __builtin_amdgcn_cvt_f32_fp8(p, 0);
      float fy = __builtin_amdgcn_cvt_f32_fp8(p, 1);
      float fz = __builtin_amdgcn_cvt_f32_fp8(p, 2);
      float fw = __builtin_amdgcn_cvt_f32_fp8(p, 3);
      s = fmaf(fx, fx, s); s = fmaf(fy, fy, s);
      s = fmaf(fz, fz, s); s = fmaf(fw, fw, s);
    }
#pragma unroll
    for (int off = 32; off; off >>= 1) s += __shfl_down(s, off);
    if (lane == 0) { sqv[r] = s; wsum += s; }
  }
  if (lane == 0) wsq[wave] = wsum;
  __syncthreads();
  if (tid == 0) sqpart[blockIdx.x] = (wsq[0] + wsq[1]) + (wsq[2] + wsq[3]);
}

// ---------------------------------------------------------------------------
// Kernel B: fused Gram + MMD, MX-fp8. R5: 128x256 block tile, 512 threads,
// 8 waves of UNCHANGED 64x64 wave tiles (2x4 wave grid). Each block computes
// tile pair (by, 2c),(by, 2c+1); the A panel is staged once and shared ->
// staged bytes/output -25%, barrier-drains/output -50%, blocks 2080->1056.
// LDS 48KB+scalars -> 3 blocks/CU = 24 waves/CU (VGPR ~84 allows 6/SIMD=24;
// caps coincide). Invalid second tiles (bx1 > by, 32 singleton rows) are
// computed on valid memory (bx1 <= 63 always) and masked by per-wave f=0.
// Per-wave staging/frag/MFMA maps are VERBATIM from the validated R0 kernel;
// only row-sourcing, wave grid, pair decode, and per-wave sign/weight are new.
// Dropped vs R4: XCD swizzle (xb is L3-fit: m160 says swizzle costs there),
// tail sqpart-reduce (bwsh back to wave-0-before-loop, hidden under staging).
// MFMA: mfma_scale_f32_16x16x128_f8f6f4, unit E8M0 scales (exact fp8 GEMM).
// C/D: col = lane&15, row = q*4 + v.
// ---------------------------------------------------------------------------
__global__ __launch_bounds__(512) void mmd_kernel(const u8* __restrict__ xb,
                                                  const float* __restrict__ sqv,
                                                  const float* __restrict__ sqpart,
                                                  float* __restrict__ tilesum) {
  // rows 0..127: A panel (rowbase+r); rows 128..383: B panel (colb + r-128)
  __shared__ __align__(16) u8 s[384 * BKB];      // 48 KB
  __shared__ float wred[8];
  __shared__ float bwsh;

  // pair decode: p -> (by, c). Rows come in equal-length pairs:
  // double-row u covers by=2u (c=0..u) then by=2u+1 (c=0..u);
  // cumulative before u is u(u+1).
  const int p = (int)blockIdx.x;
  int u = (int)((sqrtf(4.f * (float)p + 1.f) - 1.f) * 0.5f);
  while ((u + 1) * (u + 2) <= p) ++u;
  while (u * (u + 1) > p) --u;
  const int o  = p - u * (u + 1);
  const int by = 2 * u + (o > u ? 1 : 0);
  const int c  = (o > u) ? (o - (u + 1)) : o;

  const int tid  = threadIdx.x;
  const int lane = tid & 63;
  const int wave = tid >> 6;         // 0..7
  const int m16  = lane & 15;        // MFMA m/n index
  const int q    = lane >> 4;        // quad: k-block owner
  const int m8   = (lane >> 3) & 1;  // row's region half
  const int w7   = lane & 7;
  const int wrow = (wave >> 2) * 64;     // 0 or 64   (2 row groups)
  const int wcol = (wave & 3) * 64;      // 0,64,128,192 (4 col groups)
  const int rowbase = by * TILE;         // A rows
  const int colb    = c * 256;           // B rows (256-col pair)

  // ---- bandwidth from sqpart (wave 0, before K-loop; visible after first
  // barrier). R0-validated placement: latency hides under kt=0 staging.
  if (tid < 64) {
    float S = 0.f;
#pragma unroll
    for (int i = 0; i < 16; ++i) S += sqpart[tid * 16 + i];
#pragma unroll
    for (int off = 32; off; off >>= 1) S += __shfl_down(S, off);
    if (tid == 0) {
      double sumL2 = 2.0 * 8192.0 * (double)S;   // ||colsum||^2 term ~1e-4 rel, dropped
      double bwv = sumL2 / (8192.0 * 8192.0 - 8192.0) / 4.0;
      // -(1/16)/bandwidth, log2(e) folded in for exp2f epilogue
      bwsh = (float)(-0.0625 * 1.4426950408889634 / bwv);
    }
  }

  f32x4 acc[4][4];
#pragma unroll
  for (int mi = 0; mi < 4; ++mi)
#pragma unroll
    for (int ni = 0; ni < 4; ++ni) acc[mi][ni] = f32x4{0.f, 0.f, 0.f, 0.f};

  // staging: 384 rows / 8 waves = 48 rows/wave = 6 issues of 8 rows.
  // Issue i covers LDS rows 48*wave + 8*i + rr (rr = lane>>3); lane writes
  // slot w7 of row rr -> fetch global chunk tau^-1(w7^rr) (R0-verbatim map):
  //   uu = w7^rr; chunk = (uu&3)*2 + (uu>>2)
  const int rr = lane >> 3;
  const int uu = w7 ^ rr;
  const int ch = ((uu & 3) << 1) | (uu >> 2);
  const u8* gP[6];
#pragma unroll
  for (int i = 0; i < 6; ++i) {
    const int R = wave * 48 + i * 8 + rr;                    // LDS row 0..383
    const int srow = (R < 128) ? (rowbase + R) : (colb + (R - 128));
    gP[i] = xb + (size_t)srow * DDIM + ch * 16;
  }

  // frag read offsets (R0-verbatim): frag row = m8*8 + w7; chunk 2q at slot
  // q^w7 (lo regs), chunk 2q+1 at slot (q^w7)^4 (hi regs)
  const int sl1  = q ^ w7;
  const int o_lo = sl1 * 16;
  const int o_hi = (sl1 ^ 4) * 16;
  const int aoff = ((wrow >> 3) + m8) * 1024 + w7 * 128;            // + mi*2048
  const int boff = 128 * BKB + ((wcol >> 3) + m8) * 1024 + w7 * 128;// + ni*2048

#pragma unroll 1
  for (int kt = 0; kt < NKT; ++kt) {
#pragma unroll
    for (int i = 0; i < 6; ++i)
      __builtin_amdgcn_global_load_lds(AS1(gP[i] + kt * BKB),
                                       AS3(s + (wave * 6 + i) * 1024), 16, 0, 0);
    __syncthreads();
    i32x8 af[4], bf[4];
#pragma unroll
    for (int mi = 0; mi < 4; ++mi) {
      const u8* pa = s + aoff + mi * 2048;
      i32x4 lo = *(const i32x4*)(pa + o_lo);
      i32x4 hi = *(const i32x4*)(pa + o_hi);
      af[mi] = __builtin_shufflevector(lo, hi, 0, 1, 2, 3, 4, 5, 6, 7);
    }
#pragma unroll
    for (int ni = 0; ni < 4; ++ni) {
      const u8* pb = s + boff + ni * 2048;
      i32x4 lo = *(const i32x4*)(pb + o_lo);
      i32x4 hi = *(const i32x4*)(pb + o_hi);
      bf[ni] = __builtin_shufflevector(lo, hi, 0, 1, 2, 3, 4, 5, 6, 7);
    }
#pragma unroll
    for (int mi = 0; mi < 4; ++mi)
#pragma unroll
      for (int ni = 0; ni < 4; ++ni)
        acc[mi][ni] = __builtin_amdgcn_mfma_scale_f32_16x16x128_f8f6f4(
            af[mi], bf[ni], acc[mi][ni],
            0, 0,                     // cbsz=fp8(e4m3), blgp=fp8(e4m3)
            0, 0x7F7F7F7F,            // opsel_a, scale_a = E8M0 unit (2^0)
            0, 0x7F7F7F7F);           // opsel_b, scale_b
    __syncthreads();
  }

  // ---- fused epilogue (C/D: col = lane&15, row = q*4 + v) ----
  const float nib = bwsh;
  float sqc[4];
#pragma unroll
  for (int ni = 0; ni < 4; ++ni) sqc[ni] = sqv[colb + wcol + ni * 16 + m16];

  float tsum = 0.f;
#pragma unroll
  for (int mi = 0; mi < 4; ++mi) {
#pragma unroll
    for (int v = 0; v < 4; ++v) {
      const float sqr = sqv[rowbase + wrow + mi * 16 + q * 4 + v];
#pragma unroll
      for (int ni = 0; ni < 4; ++ni) {
        const float L2 = fmaf(-2.f, acc[mi][ni][v], sqr + sqc[ni]);
        const float e16 = exp2f(L2 * nib);      // log2e pre-folded into nib
        const float e8 = e16 * e16;
        const float e4 = e8 * e8;
        const float e2 = e4 * e4;
        const float e1 = e2 * e2;
        tsum += (e16 + e8) + (e4 + e2) + e1;
      }
    }
  }
#pragma unroll
  for (int off = 32; off; off >>= 1) tsum += __shfl_down(tsum, off);

  // per-wave sub-tile: absolute 128-col tile index of this wave's columns
  const int bxs   = (colb + wcol) >> 7;        // = 2c + (wcol>=128)
  const float sgn = ((by < 32) == (bxs < 32)) ? 1.f : -1.f;
  const float wgt = (bxs == by) ? 1.f : 2.f;
  const float f   = (bxs <= by) ? sgn * wgt : 0.f;   // mask invalid singleton half
  if (lane == 0) wred[wave] = f * tsum;
  __syncthreads();
  if (tid == 0) {
    float bs = 0.f;
#pragma unroll
    for (int w = 0; w < 8; ++w) bs += wred[w];
    tilesum[p] = bs;
  }
}

// ---------------------------------------------------------------------------
// Kernel C: deterministic final reduce (fixed order, double) -> mean / n^2.
// Separate dispatch (R4-validated: no cross-block ticket — 2080 same-address
// device-scope atomics serialized ~50ns each was the R1-R3 ~112us wall).
// ---------------------------------------------------------------------------
__global__ void fin_kernel(const float* __restrict__ tilesum, float* __restrict__ out) {
  __shared__ double red[4];
  const int t = threadIdx.x, lane = t & 63, wave = t >> 6;
  double s = 0.0;
  for (int i = t; i < NPAIRS; i += 256) s += (double)tilesum[i];
#pragma unroll
  for (int off = 32; off; off >>= 1) s += __shfl_down(s, off);
  if (lane == 0) red[wave] = s;
  __syncthreads();
  if (t == 0) {
    double total = red[0] + red[1] + red[2] + red[3];
    out[0] = (float)(total / 16777216.0);   // mean over n^2 = 4096^2
  }
}

extern "C" void kernel_launch(void* const* d_in, const int* in_sizes, int n_in,
                              void* d_out, int out_size, void* d_ws, size_t ws_size,
                              hipStream_t stream) {
  if (ws_size < WS_NEED) return;  // ~8.04 MB scratch
  const float* src = (const float*)d_in[0];
  const float* tgt = (const float*)d_in[1];
  char* ws = (char*)d_ws;
  u32*   xb  = (u32*)(ws + OFF_X8);
  float* sqv = (float*)(ws + OFF_SQ);
  float* sqp = (float*)(ws + OFF_SQP);
  float* ts  = (float*)(ws + OFF_TS);

  prep_kernel<<<NBLK_PREP, 256, 0, stream>>>(src, tgt, xb, sqv, sqp);
  mmd_kernel<<<NPAIRS, 512, 0, stream>>>((const u8*)xb, sqv, sqp, ts);
  fin_kernel<<<1, 256, 0, stream>>>(ts, (float*)d_out);
}

// Round 6
// 133.576 us; speedup vs baseline: 1.1132x; 1.1132x over previous
//
#include <hip/hip_runtime.h>
#include <stdint.h>

typedef unsigned char      u8;
typedef unsigned int       u32;

#define N_ROWS 8192
#define N_HALF 4096
#define DDIM   1024
#define TILE   128
#define BKB    128            // K-bytes staged per iter (=128 fp8 elems)
#define NKT    (DDIM / BKB)   // 8
#define NBLK_PREP 1024
#define NTILES (64 * 65 / 2)  // 2080 triangular 128x128 tiles

typedef int   i32x4 __attribute__((ext_vector_type(4)));
typedef int   i32x8 __attribute__((ext_vector_type(8)));
typedef float f32x4 __attribute__((ext_vector_type(4)));

// ---- workspace (8.04 MB): every byte written before read; zero atomics ----
#define OFF_X8   ((size_t)0)
#define SZ_X8    ((size_t)N_ROWS * DDIM)          // 8 MB fp8 [source;target]
#define OFF_SQ   (SZ_X8)                          // 8192 f32 row sq-norms (fp8-consistent)
#define OFF_SQP  (OFF_SQ + (size_t)N_ROWS * 4)    // sqpart[1024]
#define OFF_TS   (OFF_SQP + (size_t)NBLK_PREP * 4)// tilesum[2080]
#define WS_NEED  (OFF_TS + (size_t)NTILES * 4)

#define AS1(p) ((__attribute__((address_space(1))) void*)(p))
#define AS3(p) ((__attribute__((address_space(3))) void*)(p))

// ---------------------------------------------------------------------------
// Kernel A: fp32 -> fp8(e4m3, RNE HW cvt) copy, row sq-norms from DEQUANTIZED
// fp8 values (keeps diagonal L2 ~ 0), per-block sum-of-sq partial.
// 1024 blocks x 256 threads, 2 rows/wave. (R0-validated, untouched)
// ---------------------------------------------------------------------------
__global__ __launch_bounds__(256) void prep_kernel(const float* __restrict__ src,
                                                   const float* __restrict__ tgt,
                                                   u32* __restrict__ xb,
                                                   float* __restrict__ sqv,
                                                   float* __restrict__ sqpart) {
  __shared__ float wsq[4];
  const int tid  = threadIdx.x;
  const int lane = tid & 63;
  const int wave = tid >> 6;
  const int gw   = blockIdx.x * 4 + wave;     // 0..4095
  float wsum = 0.f;                           // valid on lane 0
#pragma unroll
  for (int rr = 0; rr < 2; ++rr) {
    const int r = gw * 2 + rr;                // 0..8191
    const float* rowp = (r < N_HALF) ? (src + (size_t)r * DDIM)
                                     : (tgt + (size_t)(r - N_HALF) * DDIM);
    float s = 0.f;
#pragma unroll
    for (int chn = 0; chn < 4; ++chn) {
      const int c0 = chn * 256 + lane * 4;
      float4 v = *(const float4*)(rowp + c0);
      int p = __builtin_amdgcn_cvt_pk_fp8_f32(v.x, v.y, 0, false);
      p     = __builtin_amdgcn_cvt_pk_fp8_f32(v.z, v.w, p, true);
      xb[(size_t)r * 256 + (c0 >> 2)] = (u32)p;
      float fx = __builtin_amdgcn_cvt_f32_fp8(p, 0);
      float fy = __builtin_amdgcn_cvt_f32_fp8(p, 1);
      float fz = __builtin_amdgcn_cvt_f32_fp8(p, 2);
      float fw = __builtin_amdgcn_cvt_f32_fp8(p, 3);
      s = fmaf(fx, fx, s); s = fmaf(fy, fy, s);
      s = fmaf(fz, fz, s); s = fmaf(fw, fw, s);
    }
#pragma unroll
    for (int off = 32; off; off >>= 1) s += __shfl_down(s, off);
    if (lane == 0) { sqv[r] = s; wsum += s; }
  }
  if (lane == 0) wsq[wave] = wsum;
  __syncthreads();
  if (tid == 0) sqpart[blockIdx.x] = (wsq[0] + wsq[1]) + (wsq[2] + wsq[3]);
}

// ---------------------------------------------------------------------------
// Kernel B: fused Gram + MMD, MX-fp8. R6: COUNTED-vmcnt double-buffer (T3+T4).
// R1/R2 tested dbuf with __syncthreads (implicit vmcnt(0) on just-issued
// loads = full drain every round -> pure occupancy loss, 114us). This is the
// untested half of the lever [m218: counted-vs-drain0 = +38-73%; "T3's gain
// IS T4"]. Per round:
//   COMPUTE buf[cur] -> s_barrier (WAR: all reads done)
//   -> STAGE(buf[cur], kt+2) -> s_waitcnt vmcnt(8)  [waits on loads issued
//      one FULL round earlier -> L2/L3 latency covered by compute]
//   -> s_barrier (publish staged buffer to all waves)
// Exactly 8 global_load_lds per wave per round makes vmcnt(8) literal.
// Buffers are named arrays (static LDS bases, rule #20). Barriers are
// asm volatile("s_barrier":::"memory") so the compiler cannot move LDS
// reads/stages across them (rule #18 analog). vmcnt(0) fence after the
// bwsh reduce zeroes the per-wave outstanding count before the prologue.
// Count audit (per wave): prologue +8(kt0)+8(kt1), wait(8) -> kt0 done.
// Round kt: +8(kt+2)=16, wait(8) -> kt+1 done. kt=6: no stage, wait(0)
// drains kt7. kt=7: compute, exit. Everything else is R0-verbatim.
// MFMA: mfma_scale_f32_16x16x128_f8f6f4, unit E8M0 scales (exact fp8 GEMM).
// C/D: col = lane&15, row = q*4 + v.
// ---------------------------------------------------------------------------
__global__ __launch_bounds__(256) void mmd_kernel(const u8* __restrict__ xb,
                                                  const float* __restrict__ sqv,
                                                  const float* __restrict__ sqpart,
                                                  float* __restrict__ tilesum) {
  __shared__ __align__(16) u8 sA0[TILE * BKB];   // 16 KB  kt even A
  __shared__ __align__(16) u8 sB0[TILE * BKB];   // 16 KB  kt even B
  __shared__ __align__(16) u8 sA1[TILE * BKB];   // 16 KB  kt odd  A
  __shared__ __align__(16) u8 sB1[TILE * BKB];   // 16 KB  kt odd  B
  __shared__ float wred[4];
  __shared__ float bwsh;

  // triangular decode: block t -> (by, bx) with by >= bx  (R0: no swizzle)
  const int t = (int)blockIdx.x;
  int by = (int)((sqrtf(8.f * (float)t + 1.f) - 1.f) * 0.5f);
  while ((by + 1) * (by + 2) / 2 <= t) ++by;
  while (by * (by + 1) / 2 > t) --by;
  const int bx = t - by * (by + 1) / 2;

  const int tid  = threadIdx.x;
  const int lane = tid & 63;
  const int wave = tid >> 6;
  const int m16  = lane & 15;        // MFMA m/n index
  const int q    = lane >> 4;        // quad: k-block owner
  const int m8   = (lane >> 3) & 1;  // row's region half
  const int w7   = lane & 7;
  const int wrow = (wave >> 1) * 64; // wave's 64x64 quadrant
  const int wcol = (wave & 1) * 64;
  const int rowbase = by * TILE;
  const int colbase = bx * TILE;

  // ---- bandwidth from sqpart (wave 0, before K-loop; R0-validated spot) ----
  if (tid < 64) {
    float S = 0.f;
#pragma unroll
    for (int i = 0; i < 16; ++i) S += sqpart[tid * 16 + i];
#pragma unroll
    for (int off = 32; off; off >>= 1) S += __shfl_down(S, off);
    if (tid == 0) {
      double sumL2 = 2.0 * 8192.0 * (double)S;   // ||colsum||^2 term ~1e-4 rel, dropped
      double bwv = sumL2 / (8192.0 * 8192.0 - 8192.0) / 4.0;
      bwsh = (float)(-0.0625 * 1.4426950408889634 / bwv);  // -(1/16)/bw * log2e
    }
  }

  f32x4 acc[4][4];
#pragma unroll
  for (int mi = 0; mi < 4; ++mi)
#pragma unroll
    for (int ni = 0; ni < 4; ++ni) acc[mi][ni] = f32x4{0.f, 0.f, 0.f, 0.f};

  // staging map (R0-verbatim): issue i covers rows wave*32+i*8+rr; lane
  // writes slot w7 of row rr -> fetch global chunk tau^-1(w7^rr):
  //   uu = w7^rr; chunk = (uu&3)*2 + (uu>>2)
  const int rr = lane >> 3;
  const int uu = w7 ^ rr;
  const int ch = ((uu & 3) << 1) | (uu >> 2);
  const u8* gA[4];
  const u8* gB[4];
#pragma unroll
  for (int i = 0; i < 4; ++i) {
    const int ra = rowbase + wave * 32 + i * 8 + rr;
    const int rb = colbase + wave * 32 + i * 8 + rr;
    gA[i] = xb + (size_t)ra * DDIM + ch * 16;
    gB[i] = xb + (size_t)rb * DDIM + ch * 16;
  }

  // frag read offsets (R0-verbatim)
  const int sl1  = q ^ w7;
  const int o_lo = sl1 * 16;
  const int o_hi = (sl1 ^ 4) * 16;
  const int aoff = ((wrow >> 3) + m8) * 1024 + w7 * 128;  // + mi*2048
  const int boff = ((wcol >> 3) + m8) * 1024 + w7 * 128;  // + ni*2048

#define STAGE2(dA, dB, ktc)                                                      \
  _Pragma("unroll")                                                              \
  for (int i = 0; i < 4; ++i) {                                                  \
    __builtin_amdgcn_global_load_lds(AS1(gA[i] + (ktc) * BKB),                   \
        AS3(dA + (wave * 4 + i) * 1024), 16, 0, 0);                              \
    __builtin_amdgcn_global_load_lds(AS1(gB[i] + (ktc) * BKB),                   \
        AS3(dB + (wave * 4 + i) * 1024), 16, 0, 0);                              \
  }

#define COMPUTE(srcA, srcB)                                                      \
  do {                                                                           \
    i32x8 af[4], bf[4];                                                          \
    _Pragma("unroll")                                                            \
    for (int mi = 0; mi < 4; ++mi) {                                             \
      const u8* pa = srcA + aoff + mi * 2048;                                    \
      i32x4 lo = *(const i32x4*)(pa + o_lo);                                     \
      i32x4 hi = *(const i32x4*)(pa + o_hi);                                     \
      af[mi] = __builtin_shufflevector(lo, hi, 0, 1, 2, 3, 4, 5, 6, 7);          \
    }                                                                            \
    _Pragma("unroll")                                                            \
    for (int ni = 0; ni < 4; ++ni) {                                             \
      const u8* pb = srcB + boff + ni * 2048;                                    \
      i32x4 lo = *(const i32x4*)(pb + o_lo);                                     \
      i32x4 hi = *(const i32x4*)(pb + o_hi);                                     \
      bf[ni] = __builtin_shufflevector(lo, hi, 0, 1, 2, 3, 4, 5, 6, 7);          \
    }                                                                            \
    _Pragma("unroll")                                                            \
    for (int mi = 0; mi < 4; ++mi)                                               \
      _Pragma("unroll")                                                          \
      for (int ni = 0; ni < 4; ++ni)                                             \
        acc[mi][ni] = __builtin_amdgcn_mfma_scale_f32_16x16x128_f8f6f4(          \
            af[mi], bf[ni], acc[mi][ni],                                         \
            0, 0, 0, 0x7F7F7F7F, 0, 0x7F7F7F7F);                                 \
  } while (0)

#define SBAR()   asm volatile("s_barrier" ::: "memory")
#define VMW(n)   asm volatile("s_waitcnt vmcnt(" #n ")" ::: "memory")

  // zero per-wave outstanding-vmem count (wave0's sqpart loads) so the
  // counted waits below are exact
  VMW(0);

  // prologue: kt0 -> buf0, kt1 -> buf1; wait kt0 (8 newest = kt1 stay in
  // flight); publish
  STAGE2(sA0, sB0, 0)
  STAGE2(sA1, sB1, 1)
  VMW(8);
  SBAR();

#pragma unroll 1
  for (int kt2 = 0; kt2 < NKT; kt2 += 2) {
    // ---- even round: kt = kt2, data in buf0 ----
    COMPUTE(sA0, sB0);
    SBAR();                          // WAR: all waves done reading buf0
    if (kt2 + 2 < NKT) {
      STAGE2(sA0, sB0, kt2 + 2)      // 16 outstanding
      VMW(8);                        // kt2+1 (buf1) loads done
    } else {
      VMW(0);                        // drain kt7 (buf1) loads
    }
    SBAR();                          // publish buf1
    // ---- odd round: kt = kt2+1, data in buf1 ----
    COMPUTE(sA1, sB1);
    SBAR();                          // WAR: all waves done reading buf1
    if (kt2 + 3 < NKT) {
      STAGE2(sA1, sB1, kt2 + 3)      // 16 outstanding
      VMW(8);                        // kt2+2 (buf0) loads done
      SBAR();                        // publish buf0
    }
    // last odd round (kt=7): nothing left to stage or wait on
  }
#undef STAGE2
#undef COMPUTE
#undef SBAR
#undef VMW

  // ---- fused epilogue (C/D: col = lane&15, row = q*4 + v) ----
  const float nib = bwsh;
  float sqc[4];
#pragma unroll
  for (int ni = 0; ni < 4; ++ni) sqc[ni] = sqv[colbase + wcol + ni * 16 + m16];

  float tsum = 0.f;
#pragma unroll
  for (int mi = 0; mi < 4; ++mi) {
#pragma unroll
    for (int v = 0; v < 4; ++v) {
      const float sqr = sqv[rowbase + wrow + mi * 16 + q * 4 + v];
#pragma unroll
      for (int ni = 0; ni < 4; ++ni) {
        const float L2 = fmaf(-2.f, acc[mi][ni][v], sqr + sqc[ni]);
        const float e16 = exp2f(L2 * nib);      // log2e pre-folded into nib
        const float e8 = e16 * e16;
        const float e4 = e8 * e8;
        const float e2 = e4 * e4;
        const float e1 = e2 * e2;
        tsum += (e16 + e8) + (e4 + e2) + e1;
      }
    }
  }
#pragma unroll
  for (int off = 32; off; off >>= 1) tsum += __shfl_down(tsum, off);
  if (lane == 0) wred[wave] = tsum;
  __syncthreads();
  if (tid == 0) {
    const float bs = (wred[0] + wred[1]) + (wred[2] + wred[3]);
    const float sgn = ((by < 32) == (bx < 32)) ? 1.f : -1.f;
    const float wgt = (bx == by) ? 1.f : 2.f;
    tilesum[t] = sgn * wgt * bs;
  }
}

// ---------------------------------------------------------------------------
// Kernel C: deterministic final reduce (fixed order, double) -> mean / n^2.
// Separate dispatch (R4-validated: no cross-block ticket).
// ---------------------------------------------------------------------------
__global__ void fin_kernel(const float* __restrict__ tilesum, float* __restrict__ out) {
  __shared__ double red[4];
  const int t = threadIdx.x, lane = t & 63, wave = t >> 6;
  double s = 0.0;
  for (int i = t; i < NTILES; i += 256) s += (double)tilesum[i];
#pragma unroll
  for (int off = 32; off; off >>= 1) s += __shfl_down(s, off);
  if (lane == 0) red[wave] = s;
  __syncthreads();
  if (t == 0) {
    double total = red[0] + red[1] + red[2] + red[3];
    out[0] = (float)(total / 16777216.0);   // mean over n^2 = 4096^2
  }
}

extern "C" void kernel_launch(void* const* d_in, const int* in_sizes, int n_in,
                              void* d_out, int out_size, void* d_ws, size_t ws_size,
                              hipStream_t stream) {
  if (ws_size < WS_NEED) return;  // ~8.04 MB scratch
  const float* src = (const float*)d_in[0];
  const float* tgt = (const float*)d_in[1];
  char* ws = (char*)d_ws;
  u32*   xb  = (u32*)(ws + OFF_X8);
  float* sqv = (float*)(ws + OFF_SQ);
  float* sqp = (float*)(ws + OFF_SQP);
  float* ts  = (float*)(ws + OFF_TS);

  prep_kernel<<<NBLK_PREP, 256, 0, stream>>>(src, tgt, xb, sqv, sqp);
  mmd_kernel<<<NTILES, 256, 0, stream>>>((const u8*)xb, sqv, sqp, ts);
  fin_kernel<<<1, 256, 0, stream>>>(ts, (float*)d_out);
}